// Round 4
// baseline (89.266 us; speedup 1.0000x reference)
//
#include <hip/hip_runtime.h>

#define Hn 28
#define PQ 784     // 28*28
#define NI 128     // B*I

typedef __attribute__((ext_vector_type(8))) short short8v;   // 8 bf16 (4 VGPRs)
typedef __attribute__((ext_vector_type(4))) short short4v;   // 4 bf16
typedef __attribute__((ext_vector_type(4))) float float4v;   // MFMA C/D

__device__ __forceinline__ short f2bf(float x) {
    union { float f; unsigned u; } a; a.f = x;
    unsigned r = a.u + 0x7FFF + ((a.u >> 16) & 1);   // RNE
    return (short)(r >> 16);
}

// tanh-form gelu: x * (1 - 1/(exp2(x*(k0 + k1*x^2)) + 1))
__device__ __forceinline__ float gelu_fast(float x) {
    const float x2 = x * x;
    const float u  = x * fmaf(x2, 0.1029446f, 2.3022077f);
    const float t  = __builtin_amdgcn_exp2f(u);
    const float r  = __builtin_amdgcn_rcpf(t + 1.0f);
    return fmaf(-x, r, x);
}

// blocks 0..27 (s-major): vTb[s][ni][p(pad32)] = bf16(v[ni][p][s]) with fully
// coalesced 2B stores; Vsum[s][ni] = sum_p v (fp32). block 28: W2b = bf16(W2).
__global__ __launch_bounds__(256) void prep_kernel(
    const float* __restrict__ v, const float* __restrict__ W2,
    short* __restrict__ vTb, short* __restrict__ W2b, float* __restrict__ Vsum)
{
    const int b = blockIdx.x;
    const int t = threadIdx.x;
    if (b == Hn) {   // W2 fp32 -> bf16, coalesced
        #pragma unroll 4
        for (int e = t; e < 8192; e += 256) {
            const float2 f = ((const float2*)W2)[e];
            short2 h; h.x = f2bf(f.x); h.y = f2bf(f.y);
            ((short2*)W2b)[e] = h;
        }
        return;
    }
    const int s = b;
    short* dst = vTb + s * (NI * 32);
    #pragma unroll
    for (int k = 0; k < 16; ++k) {
        const int idx = t + 256 * k;          // 0..4095
        const int ni = idx >> 5;
        const int p = idx & 31;
        short val = 0;
        if (p < Hn) val = f2bf(v[ni * PQ + p * Hn + s]);
        dst[idx] = val;                       // contiguous 2B stores
    }
    if (t < NI) {                             // fp32 column sums (L1-hot lines)
        const int ni = t;
        float acc = 0.0f;
        #pragma unroll
        for (int p = 0; p < Hn; ++p) acc += v[ni * PQ + p * Hn + s];
        Vsum[s * NI + ni] = acc;
    }
}

// One block per (r,s). LDS = 10240+5120+16512+4096+512 = 36480 B -> 4 blocks/CU.
__global__ __launch_bounds__(256, 4) void fused_kernel(
    const short* __restrict__ vTb, const short* __restrict__ W2b,
    const float* __restrict__ Vsum,
    const float* __restrict__ W1, const float* __restrict__ b1,
    const float* __restrict__ b2, const float* __restrict__ bias,
    float* __restrict__ out)
{
    __shared__ short sV[NI * 40];       // [ni][p] pad40 bf16  10240 B
    __shared__ short sHt[64 * 40];      // [c][p]  pad40 bf16   5120 B
    __shared__ short sTa[8 * 1032];     // [n8][k=c*16+i] bf16 16512 B
    __shared__ float sRed[4 * 256];     // per-wave partials    4096 B
    __shared__ float sVs[NI];           //                       512 B

    const int t = threadIdx.x;
    const int rs = blockIdx.x;
    const int r = rs / Hn;
    const int s = rs - r * Hn;

    // ---- stage V slice: global [s][ni][p(32)] (contiguous 8KB) -> sV rows stride 40
    {
        const short* src = vTb + s * (NI * 32);
        #pragma unroll
        for (int j = 0; j < 2; ++j) {
            const int idx = t + 256 * j;       // 0..511
            const int ni = idx >> 2;
            const int ko = (idx & 3) * 8;
            *(short8v*)&sV[ni * 40 + ko] = *(const short8v*)(src + ni * 32 + ko);
        }
    }
    if (t < NI) sVs[t] = Vsum[s * NI + t];

    // ---- phase B: sHt[c][p] = bf16( sum_q gelu(...) ), zero p 28..31
    {
        const int c = t & 63;
        const int pg = t >> 6;               // 4 groups x 7 p
        const float w10 = W1[c];
        const float w11 = W1[64 + c];
        const float w12 = W1[128 + c];
        const float w13 = W1[192 + c];
        const float inv = 1.0f / 28.0f;
        const float base_rs = ((r + 0.5f) * inv) * w12 + ((s + 0.5f) * inv) * w13 + b1[c];
        const float w10i = inv * w10;
        const float w11i = inv * w11;
        #pragma unroll 1                     // keep code size down; q-unroll gives ILP
        for (int pi = 0; pi < 7; ++pi) {
            const int p = pg * 7 + pi;
            const float base = fmaf((float)p + 0.5f, w10i, base_rs);
            float acc = 0.0f;
            #pragma unroll
            for (int q = 0; q < Hn; ++q) {
                acc += gelu_fast(fmaf((float)q + 0.5f, w11i, base));
            }
            sHt[c * 40 + p] = f2bf(acc);
        }
        if (pg == 3) *(uint2*)&sHt[c * 40 + 28] = make_uint2(0u, 0u);
    }
    __syncthreads();

    // ---- phase D (MFMA): T[ni][c] = sum_p V[ni][p] * H[p][c]
    const int w  = t >> 6;          // wave 0..3
    const int l  = t & 63;
    const int lm = l & 15;
    const int q  = l >> 4;
    const int k0 = q * 8;

    {
        short8v aF[2], bF[4];
        aF[0] = *(const short8v*)&sV[(32 * w + lm) * 40 + k0];
        aF[1] = *(const short8v*)&sV[(32 * w + 16 + lm) * 40 + k0];
        #pragma unroll
        for (int nt = 0; nt < 4; ++nt)
            bF[nt] = *(const short8v*)&sHt[(16 * nt + lm) * 40 + k0];

        float4v accD[2][4];
        #pragma unroll
        for (int mt = 0; mt < 2; ++mt)
            #pragma unroll
            for (int nt = 0; nt < 4; ++nt)
                accD[mt][nt] = __builtin_amdgcn_mfma_f32_16x16x32_bf16(
                    aF[mt], bF[nt], (float4v)(0.0f), 0, 0, 0);

        // pack T to sTa[n8][c*16+i]: ni = 32w+16mt+4q+reg -> n8=2w+mt, i=4q+reg.
        // regs are consecutive i -> one 8B ds_write_b64 per (mt,nt).
        #pragma unroll
        for (int mt = 0; mt < 2; ++mt) {
            const int n8 = 2 * w + mt;
            #pragma unroll
            for (int nt = 0; nt < 4; ++nt) {
                const int c = 16 * nt + lm;
                short4v pk;
                pk[0] = f2bf(accD[mt][nt][0]);
                pk[1] = f2bf(accD[mt][nt][1]);
                pk[2] = f2bf(accD[mt][nt][2]);
                pk[3] = f2bf(accD[mt][nt][3]);
                *(short4v*)&sTa[n8 * 1032 + c * 16 + 4 * q] = pk;
            }
        }
    }
    __syncthreads();

    // ---- phase D2 (MFMA): out[n8][o] = sum_k Ta[n8][k] * W2b[k][o], K=1024 split over waves
    float4v accO = (float4v)(0.0f);
    #pragma unroll
    for (int st = 0; st < 8; ++st) {
        const int kb = w * 256 + st * 32 + k0;
        const short8v a = *(const short8v*)&sTa[(lm & 7) * 1032 + kb];  // rows m>=8: dup, unused
        const int c  = kb >> 4;
        const int i0 = kb & 15;                                        // 0 or 8
        const short8v bfr = *(const short8v*)&W2b[c * 256 + lm * 16 + i0];
        accO = __builtin_amdgcn_mfma_f32_16x16x32_bf16(a, bfr, accO, 0, 0, 0);
    }
    #pragma unroll
    for (int reg = 0; reg < 4; ++reg) {
        const int m = q * 4 + reg;                 // 0..15, valid m<8
        sRed[w * 256 + m * 16 + lm] = accO[reg];
    }
    __syncthreads();

    // ---- E: reduce 4 wave-partials, add b2 term + bias, store
    if (t < NI) {
        const int n8 = t >> 4;
        const int o  = t & 15;
        const int e  = n8 * 16 + o;
        const float tot = sRed[e] + sRed[256 + e] + sRed[512 + e] + sRed[768 + e];
        float bsum = 0.0f;
        #pragma unroll
        for (int i = 0; i < 16; ++i)
            bsum = fmaf(b2[o * 16 + i], sVs[n8 * 16 + i], bsum);
        out[(n8 * 16 + o) * PQ + rs] = (tot + 28.0f * bsum) * (1.0f / 784.0f) + bias[o];
    }
}

extern "C" void kernel_launch(void* const* d_in, const int* in_sizes, int n_in,
                              void* d_out, int out_size, void* d_ws, size_t ws_size,
                              hipStream_t stream) {
    const float* v    = (const float*)d_in[0];  // (8,16,28,28)
    const float* W1   = (const float*)d_in[1];  // (4,64)
    const float* b1   = (const float*)d_in[2];  // (64,)
    const float* W2   = (const float*)d_in[3];  // (64,256)
    const float* b2   = (const float*)d_in[4];  // (256,)
    const float* bias = (const float*)d_in[5];  // (16,1,1)
    float* out = (float*)d_out;                 // (8,16,28,28) fp32

    char* ws = (char*)d_ws;
    short* vTb  = (short*)(ws);                 // 28*128*32*2 = 229376 B
    short* W2b  = (short*)(ws + 229376);        // 16384*2     =  32768 B
    float* Vsum = (float*)(ws + 262144);        // 28*128*4    =  14336 B

    prep_kernel<<<Hn + 1, 256, 0, stream>>>(v, W2, vTb, W2b, Vsum);
    fused_kernel<<<PQ, 256, 0, stream>>>(vTb, W2b, Vsum, W1, b1, b2, bias, out);
}

// Round 5
// 72.936 us; speedup vs baseline: 1.2239x; 1.2239x over previous
//
#include <hip/hip_runtime.h>

#define Hn 28
#define PQ 784     // 28*28
#define NI 128     // B*I

typedef __attribute__((ext_vector_type(8))) short short8v;   // 8 bf16 (4 VGPRs)
typedef __attribute__((ext_vector_type(4))) float float4v;   // MFMA C/D

__device__ __forceinline__ short f2bf(float x) {
    union { float f; unsigned u; } a; a.f = x;
    unsigned r = a.u + 0x7FFF + ((a.u >> 16) & 1);   // RNE
    return (short)(r >> 16);
}

// block ni<128: vTb[s][ni][p(pad32)] = bf16(v[ni][p][s]); Vsum[s][ni] = sum_p v.
// block 128: W2b = bf16(W2).   (R3 version — measured best)
__global__ __launch_bounds__(256) void prep_kernel(
    const float* __restrict__ v, const float* __restrict__ W2,
    short* __restrict__ vTb, short* __restrict__ W2b, float* __restrict__ Vsum)
{
    const int b = blockIdx.x;
    const int t = threadIdx.x;
    if (b == NI) {   // W2 fp32 -> bf16, coalesced
        for (int e = t; e < 8192; e += 256) {
            const float2 f = ((const float2*)W2)[e];
            short2 h; h.x = f2bf(f.x); h.y = f2bf(f.y);
            ((short2*)W2b)[e] = h;
        }
        return;
    }
    const int ni = b;
    for (int e = t; e < PQ; e += 256) {   // coalesced read, scattered 2B write
        const int p = e / Hn;
        const int s = e - p * Hn;
        vTb[s * (NI * 32) + ni * 32 + p] = f2bf(v[ni * PQ + e]);
    }
    if (t < Hn) {   // zero p-pad 28..31 (8B store, 8-aligned)
        *(uint2*)(vTb + t * (NI * 32) + ni * 32 + 28) = make_uint2(0u, 0u);
    }
    if (t < Hn) {   // column sums for the b2 term
        const int s = t;
        float acc = 0.0f;
        #pragma unroll
        for (int p = 0; p < Hn; ++p) acc += v[ni * PQ + p * Hn + s];
        Vsum[s * NI + ni] = acc;
    }
}

// One block per (r,s). LDS = 10240+5120+16512+4096+512 = 36480 B -> 4 blocks/CU.
__global__ __launch_bounds__(256, 4) void fused_kernel(
    const short* __restrict__ vTb, const short* __restrict__ W2b,
    const float* __restrict__ Vsum,
    const float* __restrict__ W1, const float* __restrict__ b1,
    const float* __restrict__ b2, const float* __restrict__ bias,
    float* __restrict__ out)
{
    __shared__ short sV[NI * 40];       // [ni][p] pad40 bf16  10240 B
    __shared__ short sHt[64 * 40];      // [c][p]  pad40 bf16   5120 B
    __shared__ short sTa[8 * 1032];     // [n8][k=c*16+i] bf16 16512 B
    __shared__ float sRed[4 * 256];     // per-wave partials    4096 B
    __shared__ float sVs[NI];           //                       512 B

    const int t = threadIdx.x;
    const int rs = blockIdx.x;
    const int r = rs / Hn;
    const int s = rs - r * Hn;

    // ---- stage V slice: global [s][ni][p(32)] (contiguous 8KB) -> sV rows stride 40
    {
        const short* src = vTb + s * (NI * 32);
        #pragma unroll
        for (int j = 0; j < 2; ++j) {
            const int idx = t + 256 * j;       // 0..511
            const int ni = idx >> 2;
            const int ko = (idx & 3) * 8;
            *(short8v*)&sV[ni * 40 + ko] = *(const short8v*)(src + ni * 32 + ko);
        }
    }
    if (t < NI) sVs[t] = Vsum[s * NI + t];

    // ---- phase B: sHt[c][p] = bf16( Σ_q gelu(arg) ) via Euler–Maclaurin:
    //   Σ_q gelu(u+v_q) = 28·g(m) + c2·W²·g''(m) + c4·W⁴·g⁗(m),  m = u+W/2
    //   g = m·Φ(m) (erf via A&S 7.1.26, shares exp with φ),
    //   g'' = φ(m)(2−m²),  g⁗ = φ(m)(−m⁴+7m²−4)
    {
        const int c = t & 63;
        const int pg = t >> 6;               // 4 groups x 7 p
        const float w0 = W1[c];
        const float Wc = W1[64 + c];         // w1[c] (signed)
        const float w2 = W1[128 + c];
        const float w3 = W1[192 + c];
        const float inv = 1.0f / 28.0f;
        const float base = ((r + 0.5f) * inv) * w2 + ((s + 0.5f) * inv) * w3
                         + b1[c] + 0.5f * Wc;
        const float w0i = inv * w0;
        const float W2c = Wc * Wc;
        const float c2 = 1.1651786f * W2c;            // 1827/(2*784)
        const float c4 = 0.0145213f * (W2c * W2c);    // 214215.75/(614656*24)
        #pragma unroll
        for (int pi = 0; pi < 7; ++pi) {
            const int p = pg * 7 + pi;
            const float m  = fmaf((float)p + 0.5f, w0i, base);
            const float m2 = m * m;
            const float E  = __builtin_amdgcn_exp2f(m2 * -0.72134752f);  // e^{-m²/2}
            // erf(|m|/√2), A&S 7.1.26
            const float az = fabsf(m) * 0.70710678f;
            const float tt = __builtin_amdgcn_rcpf(fmaf(0.3275911f, az, 1.0f));
            float poly = fmaf(tt, 1.061405429f, -1.453152027f);
            poly = fmaf(tt, poly, 1.421413741f);
            poly = fmaf(tt, poly, -0.284496736f);
            poly = fmaf(tt, poly, 0.254829592f);
            poly = poly * tt;
            float erfv = fmaf(-poly, E, 1.0f);
            erfv = (m < 0.0f) ? -erfv : erfv;
            const float g   = 0.5f * m * (1.0f + erfv);
            const float phi = 0.39894228f * E;
            const float p4  = fmaf(-m2, m2, fmaf(7.0f, m2, -4.0f));  // −m⁴+7m²−4
            const float corr = phi * fmaf(c4, p4, c2 * (2.0f - m2));
            sHt[c * 40 + p] = f2bf(fmaf(28.0f, g, corr));
        }
        if (pg == 3) *(uint2*)&sHt[c * 40 + 28] = make_uint2(0u, 0u);
    }
    __syncthreads();

    // ---- phase D (MFMA): T[ni][c] = sum_p V[ni][p] * H[p][c]
    const int w  = t >> 6;          // wave 0..3
    const int l  = t & 63;
    const int lm = l & 15;
    const int q  = l >> 4;
    const int k0 = q * 8;

    {
        short8v aF[2], bF[4];
        aF[0] = *(const short8v*)&sV[(32 * w + lm) * 40 + k0];
        aF[1] = *(const short8v*)&sV[(32 * w + 16 + lm) * 40 + k0];
        #pragma unroll
        for (int nt = 0; nt < 4; ++nt)
            bF[nt] = *(const short8v*)&sHt[(16 * nt + lm) * 40 + k0];

        float4v accD[2][4];
        #pragma unroll
        for (int mt = 0; mt < 2; ++mt)
            #pragma unroll
            for (int nt = 0; nt < 4; ++nt)
                accD[mt][nt] = __builtin_amdgcn_mfma_f32_16x16x32_bf16(
                    aF[mt], bF[nt], (float4v)(0.0f), 0, 0, 0);

        // scatter T to sTa[n8][c*16+i]: ni = 32w+16mt+q*4+reg -> n8=2w+mt, i=q*4+reg
        #pragma unroll
        for (int mt = 0; mt < 2; ++mt) {
            const int n8 = 2 * w + mt;
            #pragma unroll
            for (int nt = 0; nt < 4; ++nt) {
                const int c = 16 * nt + lm;
                #pragma unroll
                for (int reg = 0; reg < 4; ++reg) {
                    const int i = q * 4 + reg;
                    sTa[n8 * 1032 + c * 16 + i] = f2bf(accD[mt][nt][reg]);
                }
            }
        }
    }
    __syncthreads();

    // ---- phase D2 (MFMA): out[n8][o] = sum_k Ta[n8][k] * W2b[k][o], K=1024 split over waves
    float4v accO = (float4v)(0.0f);
    #pragma unroll
    for (int st = 0; st < 8; ++st) {
        const int kb = w * 256 + st * 32 + k0;
        const short8v a = *(const short8v*)&sTa[(lm & 7) * 1032 + kb];  // rows m>=8: dup, unused
        const int c  = kb >> 4;
        const int i0 = kb & 15;                                        // 0 or 8
        const short8v bfr = *(const short8v*)&W2b[c * 256 + lm * 16 + i0];
        accO = __builtin_amdgcn_mfma_f32_16x16x32_bf16(a, bfr, accO, 0, 0, 0);
    }
    #pragma unroll
    for (int reg = 0; reg < 4; ++reg) {
        const int m = q * 4 + reg;                 // 0..15, valid m<8
        sRed[w * 256 + m * 16 + lm] = accO[reg];
    }
    __syncthreads();

    // ---- E: reduce 4 wave-partials, add b2 term + bias, store
    if (t < NI) {
        const int n8 = t >> 4;
        const int o  = t & 15;
        const int e  = n8 * 16 + o;
        const float tot = sRed[e] + sRed[256 + e] + sRed[512 + e] + sRed[768 + e];
        float bsum = 0.0f;
        #pragma unroll
        for (int i = 0; i < 16; ++i)
            bsum = fmaf(b2[o * 16 + i], sVs[n8 * 16 + i], bsum);
        out[(n8 * 16 + o) * PQ + rs] = (tot + 28.0f * bsum) * (1.0f / 784.0f) + bias[o];
    }
}

extern "C" void kernel_launch(void* const* d_in, const int* in_sizes, int n_in,
                              void* d_out, int out_size, void* d_ws, size_t ws_size,
                              hipStream_t stream) {
    const float* v    = (const float*)d_in[0];  // (8,16,28,28)
    const float* W1   = (const float*)d_in[1];  // (4,64)
    const float* b1   = (const float*)d_in[2];  // (64,)
    const float* W2   = (const float*)d_in[3];  // (64,256)
    const float* b2   = (const float*)d_in[4];  // (256,)
    const float* bias = (const float*)d_in[5];  // (16,1,1)
    float* out = (float*)d_out;                 // (8,16,28,28) fp32

    char* ws = (char*)d_ws;
    short* vTb  = (short*)(ws);                 // 28*128*32*2 = 229376 B
    short* W2b  = (short*)(ws + 229376);        // 16384*2     =  32768 B
    float* Vsum = (float*)(ws + 262144);        // 28*128*4    =  14336 B

    prep_kernel<<<NI + 1, 256, 0, stream>>>(v, W2, vTb, W2b, Vsum);
    fused_kernel<<<PQ, 256, 0, stream>>>(vTb, W2b, Vsum, W1, b1, b2, bias, out);
}

// Round 6
// 72.611 us; speedup vs baseline: 1.2294x; 1.0045x over previous
//
#include <hip/hip_runtime.h>

#define Hn 28
#define PQ 784     // 28*28
#define NI 128     // B*I

typedef __attribute__((ext_vector_type(8))) short short8v;   // 8 bf16 (4 VGPRs)
typedef __attribute__((ext_vector_type(4))) short short4v;   // 4 bf16 (b64)
typedef __attribute__((ext_vector_type(4))) float float4v;   // MFMA C/D

__device__ __forceinline__ short f2bf(float x) {
    union { float f; unsigned u; } a; a.f = x;
    unsigned r = a.u + 0x7FFF + ((a.u >> 16) & 1);   // RNE
    return (short)(r >> 16);
}

// blocks 0..127 (ni-major): LDS-tiled transpose. Coalesced fp32 tile read,
// then line-granular bf16 stores (16 lanes x short2 = one 64B line).
// block 128: W2b = bf16(W2).
__global__ __launch_bounds__(256) void prep_kernel(
    const float* __restrict__ v, const float* __restrict__ W2,
    short* __restrict__ vTb, short* __restrict__ W2b, float* __restrict__ Vsum)
{
    const int b = blockIdx.x;
    const int t = threadIdx.x;
    if (b == NI) {   // W2 fp32 -> bf16, coalesced
        for (int e = t; e < 8192; e += 256) {
            const float2 f = ((const float2*)W2)[e];
            short2 h; h.x = f2bf(f.x); h.y = f2bf(f.y);
            ((short2*)W2b)[e] = h;
        }
        return;
    }
    __shared__ float sT[Hn * 29];        // [s][p] pad29, 3248 B
    const int ni = b;
    #pragma unroll
    for (int k = 0; k < 4; ++k) {        // coalesced read of the 28x28 tile
        const int e = t + 256 * k;
        if (e < PQ) {
            const int p = e / Hn;
            const int s = e - p * Hn;
            sT[s * 29 + p] = v[ni * PQ + e];
        }
    }
    __syncthreads();
    // stores: idx -> (s = idx>>4, short-pair e2 = idx&15); 16 lanes = 64B line
    #pragma unroll
    for (int k = 0; k < 2; ++k) {
        const int idx = t + 256 * k;     // 0..511, use 448
        if (idx < Hn * 16) {
            const int s = idx >> 4;
            const int e2 = idx & 15;
            const int p0 = 2 * e2;
            short2 h;
            h.x = (p0     < Hn) ? f2bf(sT[s * 29 + p0])     : (short)0;
            h.y = (p0 + 1 < Hn) ? f2bf(sT[s * 29 + p0 + 1]) : (short)0;
            *(short2*)(vTb + s * (NI * 32) + ni * 32 + p0) = h;
        }
    }
    if (t < Hn) {                        // fp32 column sums from LDS
        const int s = t;
        float acc = 0.0f;
        #pragma unroll
        for (int p = 0; p < Hn; ++p) acc += sT[s * 29 + p];
        Vsum[s * NI + ni] = acc;
    }
}

// One block per (r,s). LDS = 10240+5120+16512+4096+512 = 36480 B -> 4 blocks/CU.
__global__ __launch_bounds__(256, 4) void fused_kernel(
    const short* __restrict__ vTb, const short* __restrict__ W2b,
    const float* __restrict__ Vsum,
    const float* __restrict__ W1, const float* __restrict__ b1,
    const float* __restrict__ b2, const float* __restrict__ bias,
    float* __restrict__ out)
{
    __shared__ short sV[NI * 40];       // [ni][p] pad40 bf16  10240 B
    __shared__ short sHt[64 * 40];      // [c][p]  pad40 bf16   5120 B
    __shared__ short sTa[8 * 1032];     // [n8][k=c*16+i] bf16 16512 B
    __shared__ float sRed[4 * 256];     // per-wave partials    4096 B
    __shared__ float sVs[NI];           //                       512 B

    const int t = threadIdx.x;
    const int rs = blockIdx.x;
    const int r = rs / Hn;
    const int s = rs - r * Hn;

    // ---- stage V slice: global [s][ni][p(32)] (contiguous 8KB) -> sV rows stride 40
    {
        const short* src = vTb + s * (NI * 32);
        #pragma unroll
        for (int j = 0; j < 2; ++j) {
            const int idx = t + 256 * j;       // 0..511
            const int ni = idx >> 2;
            const int ko = (idx & 3) * 8;
            *(short8v*)&sV[ni * 40 + ko] = *(const short8v*)(src + ni * 32 + ko);
        }
    }
    if (t < NI) sVs[t] = Vsum[s * NI + t];

    // ---- phase B: sHt[c][p] = bf16( Σ_q gelu(arg) ) via Euler–Maclaurin:
    //   Σ_q gelu(u+v_q) = 28·g(m) + c2·W²·g''(m) + c4·W⁴·g⁗(m),  m = u+W/2
    {
        const int c = t & 63;
        const int pg = t >> 6;               // 4 groups x 7 p
        const float w0 = W1[c];
        const float Wc = W1[64 + c];         // w1[c] (signed)
        const float w2 = W1[128 + c];
        const float w3 = W1[192 + c];
        const float inv = 1.0f / 28.0f;
        const float base = ((r + 0.5f) * inv) * w2 + ((s + 0.5f) * inv) * w3
                         + b1[c] + 0.5f * Wc;
        const float w0i = inv * w0;
        const float W2c = Wc * Wc;
        const float c2 = 1.1651786f * W2c;            // 1827/(2*784)
        const float c4 = 0.0145213f * (W2c * W2c);    // 214215.75/(614656*24)
        #pragma unroll
        for (int pi = 0; pi < 7; ++pi) {
            const int p = pg * 7 + pi;
            const float m  = fmaf((float)p + 0.5f, w0i, base);
            const float m2 = m * m;
            const float E  = __builtin_amdgcn_exp2f(m2 * -0.72134752f);  // e^{-m²/2}
            const float az = fabsf(m) * 0.70710678f;
            const float tt = __builtin_amdgcn_rcpf(fmaf(0.3275911f, az, 1.0f));
            float poly = fmaf(tt, 1.061405429f, -1.453152027f);
            poly = fmaf(tt, poly, 1.421413741f);
            poly = fmaf(tt, poly, -0.284496736f);
            poly = fmaf(tt, poly, 0.254829592f);
            poly = poly * tt;
            float erfv = fmaf(-poly, E, 1.0f);
            erfv = (m < 0.0f) ? -erfv : erfv;
            const float g   = 0.5f * m * (1.0f + erfv);
            const float phi = 0.39894228f * E;
            const float p4  = fmaf(-m2, m2, fmaf(7.0f, m2, -4.0f));  // −m⁴+7m²−4
            const float corr = phi * fmaf(c4, p4, c2 * (2.0f - m2));
            sHt[c * 40 + p] = f2bf(fmaf(28.0f, g, corr));
        }
        if (pg == 3) *(uint2*)&sHt[c * 40 + 28] = make_uint2(0u, 0u);
    }
    __syncthreads();

    // ---- phase D (MFMA): T[ni][c] = sum_p V[ni][p] * H[p][c]
    const int w  = t >> 6;          // wave 0..3
    const int l  = t & 63;
    const int lm = l & 15;
    const int q  = l >> 4;
    const int k0 = q * 8;

    {
        short8v aF[2], bF[4];
        aF[0] = *(const short8v*)&sV[(32 * w + lm) * 40 + k0];
        aF[1] = *(const short8v*)&sV[(32 * w + 16 + lm) * 40 + k0];
        #pragma unroll
        for (int nt = 0; nt < 4; ++nt)
            bF[nt] = *(const short8v*)&sHt[(16 * nt + lm) * 40 + k0];

        float4v accD[2][4];
        #pragma unroll
        for (int mt = 0; mt < 2; ++mt)
            #pragma unroll
            for (int nt = 0; nt < 4; ++nt)
                accD[mt][nt] = __builtin_amdgcn_mfma_f32_16x16x32_bf16(
                    aF[mt], bF[nt], (float4v)(0.0f), 0, 0, 0);

        // pack T to sTa[n8][c*16+i]: ni = 32w+16mt+4q+reg -> n8=2w+mt, i=4q+reg.
        // 4 consecutive i per (mt,nt) -> one 8B ds_write_b64.
        #pragma unroll
        for (int mt = 0; mt < 2; ++mt) {
            const int n8 = 2 * w + mt;
            #pragma unroll
            for (int nt = 0; nt < 4; ++nt) {
                const int c = 16 * nt + lm;
                short4v pk;
                pk[0] = f2bf(accD[mt][nt][0]);
                pk[1] = f2bf(accD[mt][nt][1]);
                pk[2] = f2bf(accD[mt][nt][2]);
                pk[3] = f2bf(accD[mt][nt][3]);
                *(short4v*)&sTa[n8 * 1032 + c * 16 + 4 * q] = pk;
            }
        }
    }
    __syncthreads();

    // ---- phase D2 (MFMA): out[n8][o] = sum_k Ta[n8][k] * W2b[k][o], K=1024 split over waves
    float4v accO = (float4v)(0.0f);
    #pragma unroll
    for (int st = 0; st < 8; ++st) {
        const int kb = w * 256 + st * 32 + k0;
        const short8v a = *(const short8v*)&sTa[(lm & 7) * 1032 + kb];  // rows m>=8: dup, unused
        const int c  = kb >> 4;
        const int i0 = kb & 15;                                        // 0 or 8
        const short8v bfr = *(const short8v*)&W2b[c * 256 + lm * 16 + i0];
        accO = __builtin_amdgcn_mfma_f32_16x16x32_bf16(a, bfr, accO, 0, 0, 0);
    }
    #pragma unroll
    for (int reg = 0; reg < 4; ++reg) {
        const int m = q * 4 + reg;                 // 0..15, valid m<8
        sRed[w * 256 + m * 16 + lm] = accO[reg];
    }
    __syncthreads();

    // ---- E: reduce 4 wave-partials, add b2 term + bias, store
    if (t < NI) {
        const int n8 = t >> 4;
        const int o  = t & 15;
        const int e  = n8 * 16 + o;
        const float tot = sRed[e] + sRed[256 + e] + sRed[512 + e] + sRed[768 + e];
        float bsum = 0.0f;
        #pragma unroll
        for (int i = 0; i < 16; ++i)
            bsum = fmaf(b2[o * 16 + i], sVs[n8 * 16 + i], bsum);
        out[(n8 * 16 + o) * PQ + rs] = (tot + 28.0f * bsum) * (1.0f / 784.0f) + bias[o];
    }
}

extern "C" void kernel_launch(void* const* d_in, const int* in_sizes, int n_in,
                              void* d_out, int out_size, void* d_ws, size_t ws_size,
                              hipStream_t stream) {
    const float* v    = (const float*)d_in[0];  // (8,16,28,28)
    const float* W1   = (const float*)d_in[1];  // (4,64)
    const float* b1   = (const float*)d_in[2];  // (64,)
    const float* W2   = (const float*)d_in[3];  // (64,256)
    const float* b2   = (const float*)d_in[4];  // (256,)
    const float* bias = (const float*)d_in[5];  // (16,1,1)
    float* out = (float*)d_out;                 // (8,16,28,28) fp32

    char* ws = (char*)d_ws;
    short* vTb  = (short*)(ws);                 // 28*128*32*2 = 229376 B
    short* W2b  = (short*)(ws + 229376);        // 16384*2     =  32768 B
    float* Vsum = (float*)(ws + 262144);        // 28*128*4    =  14336 B

    prep_kernel<<<NI + 1, 256, 0, stream>>>(v, W2, vTb, W2b, Vsum);
    fused_kernel<<<PQ, 256, 0, stream>>>(vTb, W2b, Vsum, W1, b1, b2, bias, out);
}